// Round 9
// baseline (217.951 us; speedup 1.0000x reference)
//
#include <hip/hip_runtime.h>
#include <stdint.h>
#include <math.h>

// ---------------- problem constants ----------------
#define B_N   16384
#define D_N   1024
#define K_N   512
#define KU_N  1024          // K*U
#define EPS_F 1e-8f
#define TEMP  0.67f
#define EULERC 0.5772156649015329f

#define HEPS  524288        // 2^19  (eps stream half)
#define HU    262144        // 2^18  (bernoulli/kumaraswamy stream half)
#define HG    8388608       // 2^23  (gumbel stream half)

typedef uint32_t u32;
typedef __attribute__((ext_vector_type(4))) float f32x4;
typedef __attribute__((ext_vector_type(4))) unsigned int u32x4;
typedef __attribute__((ext_vector_type(8))) __bf16 bf16x8;

// ---------------- threefry2x32 (JAX-exact) ----------------
#define TF_ROT(x, r) (((x) << (r)) | ((x) >> (32 - (r))))

__host__ __device__ static inline void threefry2x32(u32 k0, u32 k1,
                                                    u32 x0, u32 x1,
                                                    u32* o0, u32* o1) {
  u32 ks2 = k0 ^ k1 ^ 0x1BD11BDAu;
  x0 += k0; x1 += k1;
  x0 += x1; x1 = TF_ROT(x1, 13); x1 ^= x0;
  x0 += x1; x1 = TF_ROT(x1, 15); x1 ^= x0;
  x0 += x1; x1 = TF_ROT(x1, 26); x1 ^= x0;
  x0 += x1; x1 = TF_ROT(x1, 6);  x1 ^= x0;
  x0 += k1; x1 += ks2 + 1u;
  x0 += x1; x1 = TF_ROT(x1, 17); x1 ^= x0;
  x0 += x1; x1 = TF_ROT(x1, 29); x1 ^= x0;
  x0 += x1; x1 = TF_ROT(x1, 16); x1 ^= x0;
  x0 += x1; x1 = TF_ROT(x1, 24); x1 ^= x0;
  x0 += ks2; x1 += k0 + 2u;
  x0 += x1; x1 = TF_ROT(x1, 13); x1 ^= x0;
  x0 += x1; x1 = TF_ROT(x1, 15); x1 ^= x0;
  x0 += x1; x1 = TF_ROT(x1, 26); x1 ^= x0;
  x0 += x1; x1 = TF_ROT(x1, 6);  x1 ^= x0;
  x0 += k0; x1 += k1 + 3u;
  x0 += x1; x1 = TF_ROT(x1, 17); x1 ^= x0;
  x0 += x1; x1 = TF_ROT(x1, 29); x1 ^= x0;
  x0 += x1; x1 = TF_ROT(x1, 16); x1 ^= x0;
  x0 += x1; x1 = TF_ROT(x1, 24); x1 ^= x0;
  x0 += k1; x1 += ks2 + 4u;
  x0 += x1; x1 = TF_ROT(x1, 13); x1 ^= x0;
  x0 += x1; x1 = TF_ROT(x1, 15); x1 ^= x0;
  x0 += x1; x1 = TF_ROT(x1, 26); x1 ^= x0;
  x0 += x1; x1 = TF_ROT(x1, 6);  x1 ^= x0;
  x0 += ks2; x1 += k0 + 5u;
  *o0 = x0; *o1 = x1;
}

// ---------------- numeric helpers ----------------
__device__ static inline float bits_to_u01(u32 b) {
  u32 f = (b >> 9) | 0x3f800000u;
  return __uint_as_float(f) - 1.0f;
}
__device__ static inline float unif_f(u32 b, float lo, float hi) {
  float f = bits_to_u01(b);
  return fmaxf(lo, f * (hi - lo) + lo);
}
__device__ static inline float erfinv_f(float x) {
  float w = -log1pf(-x * x);
  float p;
  if (w < 5.f) {
    w -= 2.5f;
    p = 2.81022636e-08f;
    p = fmaf(p, w, 3.43273939e-07f);
    p = fmaf(p, w, -3.5233877e-06f);
    p = fmaf(p, w, -4.39150654e-06f);
    p = fmaf(p, w, 0.00021858087f);
    p = fmaf(p, w, -0.00125372503f);
    p = fmaf(p, w, -0.00417768164f);
    p = fmaf(p, w, 0.246640727f);
    p = fmaf(p, w, 1.50140941f);
  } else {
    w = sqrtf(w) - 3.f;
    p = -0.000200214257f;
    p = fmaf(p, w, 0.000100950558f);
    p = fmaf(p, w, 0.00134934322f);
    p = fmaf(p, w, -0.00367342844f);
    p = fmaf(p, w, 0.00573950773f);
    p = fmaf(p, w, -0.0076224613f);
    p = fmaf(p, w, 0.00943887047f);
    p = fmaf(p, w, 1.00167406f);
    p = fmaf(p, w, 2.83297682f);
  }
  return p * x;
}
__device__ static inline float softplus_f(float x) {
  return fmaxf(x, 0.f) + log1pf(expf(-fabsf(x)));
}
__device__ static inline float rcp_f(float x) { return __builtin_amdgcn_rcpf(x); }
__device__ static inline float sigmoid_fast(float x) {
  return rcp_f(1.f + __expf(-x));
}
__device__ static inline float digamma_f(float x) {
  float r = 0.f;
  while (x < 6.f) { r -= 1.f / x; x += 1.f; }
  float inv = 1.f / x, inv2 = inv * inv;
  return r + logf(x) - 0.5f * inv
       - inv2 * (1.f / 12.f - inv2 * (1.f / 120.f - inv2 * (1.f / 252.f)));
}
__device__ static inline unsigned short f2bf_rne(float x) {
  u32 u = __float_as_uint(x);
  u32 r = (u + 0x7fffu + ((u >> 16) & 1u)) >> 16;
  return (unsigned short)r;
}
__device__ static inline u32 cvt_pk_bf16(float lo, float hi) {
  u32 r;
  asm("v_cvt_pk_bf16_f32 %0, %1, %2" : "=v"(r) : "v"(lo), "v"(hi));
  return r;
}
__device__ static inline void gload_lds16(const void* g, void* l) {
  __builtin_amdgcn_global_load_lds(
      (const __attribute__((address_space(1))) u32*)g,
      (__attribute__((address_space(3))) u32*)l, 16, 0, 0);
}

// block-wide sum; valid result only on thread 0
__device__ static inline float block_sum(float v) {
  __shared__ float sm[16];
  int lane = threadIdx.x & 63;
  int wid = threadIdx.x >> 6;
  #pragma unroll
  for (int o = 32; o > 0; o >>= 1) v += __shfl_down(v, o, 64);
  if (lane == 0) sm[wid] = v;
  __syncthreads();
  float s = 0.f;
  if (threadIdx.x == 0) {
    int nw = (blockDim.x + 63) >> 6;
    s = sm[0];
    for (int w = 1; w < nw; ++w) s += sm[w];
  }
  return s;
}

// ---------------- kernels ----------------
// init: per-k tables, kl_sticks -> gacc[1], zero gacc[0], gacc[2]
__global__ void k_init(const float* __restrict__ conc1,
                       const float* __restrict__ conc0,
                       float* __restrict__ invA, float* __restrict__ invB,
                       float* gacc) {
  int k = threadIdx.x;  // 512
  float a = softplus_f(conc1[k]);
  float b = softplus_f(conc0[k]);
  invA[k] = 1.f / a;
  invB[k] = 1.f / b;
  float s = ((a - 1.f) / a) * (-EULERC - digamma_f(b) - 1.f / b)
          + logf(a * b + EPS_F) - (b - 1.f) / b;
  float t = block_sum(s);
  if (threadIdx.x == 0) { gacc[0] = 0.f; gacc[1] = t; gacc[2] = 0.f; }
}

// kl_z pass A: 64 chunks of 16 d's; qu computed inline (threefry + pow)
__global__ __launch_bounds__(256) void k_klz_a(const float* __restrict__ invA,
                                               const float* __restrict__ invB,
                                               float* __restrict__ P,
                                               u32 qk0, u32 qk1) {
  int idx = blockIdx.x * 256 + threadIdx.x;  // [0, 32768)
  int c = idx >> 9, k = idx & (K_N - 1);
  float iA = invA[k], iB = invB[k];
  float p = 1.f;
  int d0 = c << 4;
  for (int d = d0; d < d0 + 16; ++d) {
    int n = (d << 9) + k;
    u32 x0 = (n < HU) ? (u32)n : (u32)(n - HU);
    u32 o0, o1;
    threefry2x32(qk0, qk1, x0, x0 + HU, &o0, &o1);
    u32 bits = (n < HU) ? o0 : o1;
    float u = unif_f(bits, 1e-6f, 1.f - 1e-6f);
    p *= powf(1.f - powf(u, iB), iA);
  }
  P[idx] = p;
}

// kl_z pass B: prefix-recombined cumprod + KL sum -> atomicAdd gacc[1]
__global__ __launch_bounds__(256) void k_klz_b(const float* __restrict__ t_pi,
                                               const float* __restrict__ invA,
                                               const float* __restrict__ invB,
                                               const float* __restrict__ P,
                                               float* gacc,
                                               u32 qk0, u32 qk1) {
  int idx = blockIdx.x * 256 + threadIdx.x;  // [0, 32768)
  int c = idx >> 9, k = idx & (K_N - 1);
  float iA = invA[k], iB = invB[k];
  float prior = 1.f;
  for (int c2 = 0; c2 < c; ++c2) prior *= P[(c2 << 9) + k];
  float s = 0.f;
  int d0 = c << 4;
  for (int d = d0; d < d0 + 16; ++d) {
    int n = (d << 9) + k;
    u32 x0 = (n < HU) ? (u32)n : (u32)(n - HU);
    u32 o0, o1;
    threefry2x32(qk0, qk1, x0, x0 + HU, &o0, &o1);
    u32 bits = (n < HU) ? o0 : o1;
    float u = unif_f(bits, 1e-6f, 1.f - 1e-6f);
    prior *= powf(1.f - powf(u, iB), iA);
    float q = sigmoid_fast(t_pi[n]);
    s += q * (__logf(q + EPS_F) - __logf(prior + EPS_F));
  }
  float t = block_sum(s);
  if (threadIdx.x == 0) atomicAdd(&gacc[1], t);
}

// WzT[j][d] = z(d, j%K)*(mW[d][j]+eps*softplus(sW[d][j])) in bf16, via 64x64
// LDS transpose tile (coalesced loads AND stores); kl_weights -> gacc[0]
__global__ __launch_bounds__(256) void k_wbuildT(const float* __restrict__ mW,
                                                 const float* __restrict__ sW,
                                                 const float* __restrict__ t_pi,
                                                 unsigned short* __restrict__ WzT,
                                                 float* __restrict__ gacc,
                                                 u32 ek0, u32 ek1,
                                                 u32 uk0, u32 uk1) {
  __shared__ unsigned short tile[64][65];
  int dt = (int)blockIdx.x >> 4;   // 0..15
  int jt = (int)blockIdx.x & 15;   // 0..15
  int d0 = dt << 6, j0 = jt << 6;
  int tj = threadIdx.x & 63;
  int tr = threadIdx.x >> 6;       // 0..3
  int j = j0 + tj;
  int kk = j & (K_N - 1);
  bool lowD = (dt < 8);
  float klw = 0.f;
  #pragma unroll 4
  for (int rr = 0; rr < 16; ++rr) {
    int dl = (rr << 2) + tr;
    int d = d0 + dl;
    int n = (d << 10) + j;
    u32 x0 = lowD ? (u32)n : (u32)(n - HEPS);
    u32 o0, o1;
    threefry2x32(ek0, ek1, x0, x0 + HEPS, &o0, &o1);
    u32 ebits = lowD ? o0 : o1;
    int nz = (d << 9) + kk;
    u32 zx0 = lowD ? (u32)nz : (u32)(nz - HU);
    u32 z0, z1;
    threefry2x32(uk0, uk1, zx0, zx0 + HU, &z0, &z1);
    u32 zbits = lowD ? z0 : z1;
    float u = unif_f(zbits, 1e-6f, 1.f - 1e-6f);
    float logistic = __logf(u) - log1pf(-u);
    float z = sigmoid_fast((t_pi[nz] + logistic) * (1.f / TEMP));
    float un = unif_f(ebits, -0.99999994f, 1.0f);
    float epsn = 1.41421356f * erfinv_f(un);
    float m = mW[n], sp = softplus_f(sW[n]);
    tile[tj][dl] = f2bf_rne(z * (m + epsn * sp));
    klw += 2.f * sp - m * m - sp * sp + 1.f;
  }
  __syncthreads();
  #pragma unroll 4
  for (int rr = 0; rr < 16; ++rr) {
    int jl = (rr << 2) + tr;
    WzT[(size_t)(j0 + jl) * D_N + d0 + tj] = tile[jl][tj];
  }
  float t = block_sum(klw);
  if (threadIdx.x == 0) atomicAdd(&gacc[0], t);
}

// ---------------- MFMA GEMM: C[b][j] = sum_d A[b][d]*WzT[j][d] + bias[j] ----
// BK=64: 16 K-steps (half the sync events of BK=32), double-buffered LDS,
// raw s_barrier + counted vmcnt(8) (B(t)x4 oldest retire; A-regs(t+1)x8 stay
// in flight). LDS tiles [128 rows/cols][64 k] bf16, 8x16B chunks/row,
// XOR-swizzle chunk^=(row&7) on both write and read sides.
#define GBM 128
#define GBN 128
#define GBK 64

__global__ __launch_bounds__(256) void k_gemm(const float* __restrict__ A,
                                              const unsigned short* __restrict__ Bt,
                                              const float* __restrict__ bias,
                                              float* __restrict__ C) {
  __shared__ __align__(16) unsigned short As[2][GBM * GBK];  // 16KB each
  __shared__ __align__(16) unsigned short Bs[2][GBN * GBK];  // 16KB each

  // XCD-chunked swizzle: 8 consecutive works share an A panel on one XCD
  int f = (int)blockIdx.x;                   // 0..1023
  int wk = (f & 7) * 128 + (f >> 3);
  const int brow = (wk >> 3) * GBM;          // 128 M-tiles
  const int bcol = (wk & 7) * GBN;           // 8 N-tiles

  const int tid = threadIdx.x;
  const int lane = tid & 63;
  const int w = tid >> 6;

  // A reg-staging: thread t covers row t>>1, f32 cols (t&1)*32 + 0..31
  const int ar = tid >> 1;
  const float* gA = A + (size_t)(brow + ar) * D_N + ((tid & 1) << 5);
  const int cb = (tid & 1) << 2;             // chunk base 0 or 4
  int aoff[4];
  #pragma unroll
  for (int i = 0; i < 4; ++i)
    aoff[i] = (ar << 7) + (((cb + i) ^ (ar & 7)) << 4);

  // B staging via gload_lds: col = q*32 + (tid>>3), source chunk pre-swizzled
  const int bcl = tid >> 3;                  // 0..31 (col within 32-granule)
  const unsigned short* gB = Bt + (size_t)(bcol + bcl) * D_N
                           + (((tid & 7) ^ (bcl & 7)) << 3);
  const int bdst = (w << 10);                // wave-uniform LDS offset within issue

  f32x4 acc[4][4];
  #pragma unroll
  for (int m = 0; m < 4; ++m)
    #pragma unroll
    for (int n = 0; n < 4; ++n) acc[m][n] = (f32x4){0.f, 0.f, 0.f, 0.f};

  const int wr = (w >> 1) << 6;   // 0 or 64
  const int wc = (w & 1) << 6;    // 0 or 64
  const int fr = lane & 15;
  const int kg = lane >> 4;       // 0..3

  f32x4 av[8];

  // ---- prologue: A-regs(0); gloadB(0)->buf0; pack A(0)->buf0; A-regs(1)
  #pragma unroll
  for (int j = 0; j < 8; ++j) av[j] = *(const f32x4*)(gA + (j << 2));
  #pragma unroll
  for (int q = 0; q < 4; ++q)
    gload_lds16(gB + (size_t)(q * 32) * D_N, (char*)Bs[0] + q * 4096 + bdst);
  __builtin_amdgcn_sched_barrier(0);
  #pragma unroll
  for (int i = 0; i < 4; ++i) {
    u32x4 p;
    p.x = cvt_pk_bf16(av[2 * i].x, av[2 * i].y);
    p.y = cvt_pk_bf16(av[2 * i].z, av[2 * i].w);
    p.z = cvt_pk_bf16(av[2 * i + 1].x, av[2 * i + 1].y);
    p.w = cvt_pk_bf16(av[2 * i + 1].z, av[2 * i + 1].w);
    *(u32x4*)((char*)As[0] + aoff[i]) = p;
  }
  #pragma unroll
  for (int j = 0; j < 8; ++j) av[j] = *(const f32x4*)(gA + GBK + (j << 2));
  // outstanding: [B(0)x4 (oldest), A(1)x8]

  for (int t = 0; t < 15; ++t) {
    const int cur = t & 1;
    char* curA = (char*)As + (cur << 14);
    char* curB = (char*)Bs + (cur << 14);
    char* altA = (char*)As + ((cur ^ 1) << 14);
    char* altB = (char*)Bs + ((cur ^ 1) << 14);

    asm volatile("s_waitcnt vmcnt(8) lgkmcnt(0)" ::: "memory");
    __builtin_amdgcn_s_barrier();

    // stage B(t+1) -> alt (stays in flight across next barrier's vmcnt(8))
    {
      const unsigned short* gBn = gB + ((t + 1) << 6);
      #pragma unroll
      for (int q = 0; q < 4; ++q)
        gload_lds16(gBn + (size_t)(q * 32) * D_N, altB + q * 4096 + bdst);
    }
    __builtin_amdgcn_sched_barrier(0);

    // compute on buf[cur]: 2 k-subtiles x 16 MFMA
    #pragma unroll
    for (int h = 0; h < 2; ++h) {
      bf16x8 af[4];
      #pragma unroll
      for (int m = 0; m < 4; ++m) {
        int row = wr + m * 16 + fr;
        af[m] = *(const bf16x8*)(curA + (row << 7) + ((((h << 2) + kg) ^ (row & 7)) << 4));
      }
      #pragma unroll
      for (int n = 0; n < 4; ++n) {
        int col = wc + n * 16 + fr;
        bf16x8 bf = *(const bf16x8*)(curB + (col << 7) + ((((h << 2) + kg) ^ (col & 7)) << 4));
        #pragma unroll
        for (int m = 0; m < 4; ++m)
          acc[m][n] = __builtin_amdgcn_mfma_f32_16x16x32_bf16(af[m], bf, acc[m][n], 0, 0, 0);
      }
    }

    // pack A(t+1) (regs from iter t-1; waiting them leaves B(t+1) in flight)
    #pragma unroll
    for (int i = 0; i < 4; ++i) {
      u32x4 p;
      p.x = cvt_pk_bf16(av[2 * i].x, av[2 * i].y);
      p.y = cvt_pk_bf16(av[2 * i].z, av[2 * i].w);
      p.z = cvt_pk_bf16(av[2 * i + 1].x, av[2 * i + 1].y);
      p.w = cvt_pk_bf16(av[2 * i + 1].z, av[2 * i + 1].w);
      *(u32x4*)(altA + aoff[i]) = p;
    }
    if (t < 14) {
      const float* g = gA + ((t + 2) << 6);
      #pragma unroll
      for (int j = 0; j < 8; ++j) av[j] = *(const f32x4*)(g + (j << 2));
    }
  }

  // peeled final K-step (t=15, cur=1): only B(15)x4 outstanding -> full drain
  asm volatile("s_waitcnt vmcnt(0) lgkmcnt(0)" ::: "memory");
  __builtin_amdgcn_s_barrier();
  {
    char* curA = (char*)As + (1 << 14);
    char* curB = (char*)Bs + (1 << 14);
    #pragma unroll
    for (int h = 0; h < 2; ++h) {
      bf16x8 af[4];
      #pragma unroll
      for (int m = 0; m < 4; ++m) {
        int row = wr + m * 16 + fr;
        af[m] = *(const bf16x8*)(curA + (row << 7) + ((((h << 2) + kg) ^ (row & 7)) << 4));
      }
      #pragma unroll
      for (int n = 0; n < 4; ++n) {
        int col = wc + n * 16 + fr;
        bf16x8 bf = *(const bf16x8*)(curB + (col << 7) + ((((h << 2) + kg) ^ (col & 7)) << 4));
        #pragma unroll
        for (int m = 0; m < 4; ++m)
          acc[m][n] = __builtin_amdgcn_mfma_f32_16x16x32_bf16(af[m], bf, acc[m][n], 0, 0, 0);
      }
    }
  }

  #pragma unroll
  for (int n = 0; n < 4; ++n) {
    int col = bcol + wc + n * 16 + fr;
    float bv = bias[col];
    #pragma unroll
    for (int m = 0; m < 4; ++m) {
      int rowb = brow + wr + m * 16 + (kg << 2);
      C[(size_t)(rowb + 0) * KU_N + col] = acc[m][n].x + bv;
      C[(size_t)(rowb + 1) * KU_N + col] = acc[m][n].y + bv;
      C[(size_t)(rowb + 2) * KU_N + col] = acc[m][n].z + bv;
      C[(size_t)(rowb + 3) * KU_N + col] = acc[m][n].w + bv;
    }
  }
}

// ---------------- LWTA epilogue ----------------
// Minimal quad per thread: rows {b, b+8192} x cols {2k, 2k+1} share exactly
// 2 threefry hashes (all 4 outputs consumed). Small live state -> lean codegen.
__device__ static inline float lwta_pair(float v0, float v1, u32 ba, u32 bb,
                                         float* o0, float* o1) {
  float u0 = unif_f(ba, 1e-6f, 1.f - 1e-6f);
  float u1 = unif_f(bb, 1e-6f, 1.f - 1e-6f);
  float g0 = -__logf(-__logf(u0));
  float g1 = -__logf(-__logf(u1));
  const float it = 1.f / TEMP;
  float d = ((v1 + g1) - (v0 + g0)) * it;
  float xi0 = rcp_f(1.f + __expf(d));
  float xi1 = 1.f - xi0;
  *o0 = v0 * xi0;
  *o1 = v1 * xi1;
  float qd = v1 - v0;
  float q0 = rcp_f(1.f + __expf(qd));
  float q1 = 1.f - q0;
  const float LOG2F = 0.6931471805599453f;
  return q0 * (__logf(q0 + EPS_F) + LOG2F) + q1 * (__logf(q1 + EPS_F) + LOG2F);
}

__global__ __launch_bounds__(256) void k_epi(float* __restrict__ C,
                                             float* __restrict__ partial,
                                             u32 gk0, u32 gk1) {
  int idx = blockIdx.x * 256 + threadIdx.x;   // [0, 2^22)
  int b = idx >> 9;                           // 0..8191
  int c2 = (idx & 511) << 1;                  // 0,2,...,1022
  size_t p0 = (size_t)b * KU_N + c2;
  size_t p1 = p0 + (size_t)8192 * KU_N;
  float2 r0 = *(const float2*)&C[p0];
  float2 r1 = *(const float2*)&C[p1];
  u32 m = ((u32)b << 10) | (u32)c2;
  u32 x0a, x1a, x0b, x1b;
  threefry2x32(gk0, gk1, m,      m + HG,      &x0a, &x1a);
  threefry2x32(gk0, gk1, m + 1u, m + 1u + HG, &x0b, &x1b);
  float2 w0, w1;
  float kl = lwta_pair(r0.x, r0.y, x0a, x0b, &w0.x, &w0.y)
           + lwta_pair(r1.x, r1.y, x1a, x1b, &w1.x, &w1.y);
  *(float2*)&C[p0] = w0;
  *(float2*)&C[p1] = w1;
  float t = block_sum(kl);
  if (threadIdx.x == 0) partial[blockIdx.x] = t;
}

#define NPART 16384
__global__ __launch_bounds__(256) void k_final(const float* __restrict__ gacc,
                                               const float* __restrict__ partial,
                                               float* __restrict__ out_loss) {
  float s = 0.f;
  for (int i = threadIdx.x; i < NPART; i += 256) s += partial[i];
  float t = block_sum(s);
  if (threadIdx.x == 0) {
    float kl_weights = -0.5f * (gacc[0] * (1.f / 1048576.f));
    out_loss[0] = kl_weights / 60000.f + gacc[1] + t * (1.f / 32768.f);
  }
}

// ---------------- launch ----------------
extern "C" void kernel_launch(void* const* d_in, const int* in_sizes, int n_in,
                              void* d_out, int out_size, void* d_ws, size_t ws_size,
                              hipStream_t stream) {
  (void)in_sizes; (void)n_in; (void)out_size; (void)ws_size;
  const float* inputs = (const float*)d_in[0];
  const float* mW     = (const float*)d_in[1];
  const float* sW     = (const float*)d_in[2];
  const float* conc1  = (const float*)d_in[3];
  const float* conc0  = (const float*)d_in[4];
  const float* t_pi   = (const float*)d_in[5];
  const float* biases = (const float*)d_in[6];
  float* out = (float*)d_out;

  // rk[0..3] = split(key(42), 4)
  u32 a[4], b[4];
  for (int i = 0; i < 4; ++i)
    threefry2x32(0u, 42u, (u32)i, (u32)(i + 4), &a[i], &b[i]);
  u32 e_k0 = a[0], e_k1 = a[1];   // eps (normal)
  u32 u_k0 = a[2], u_k1 = a[3];   // bernoulli-u
  u32 q_k0 = b[0], q_k1 = b[1];   // kumaraswamy
  u32 g_k0 = b[2], g_k1 = b[3];   // gumbel

  char* wsb = (char*)d_ws;
  unsigned short* WzT = (unsigned short*)wsb;                   // 2MB
  float* P       = (float*)(wsb + (2u << 20));                  // 128KB
  float* invA    = (float*)(wsb + (2u << 20) + (128u << 10));   // 2KB
  float* invB    = (float*)(wsb + (2u << 20) + (130u << 10));   // 2KB
  float* gacc    = (float*)(wsb + (2u << 20) + (132u << 10));   // 32B
  float* partial = (float*)(wsb + (2u << 20) + (136u << 10));   // 64KB

  hipLaunchKernelGGL(k_init, dim3(1), dim3(512), 0, stream,
                     conc1, conc0, invA, invB, gacc);
  hipLaunchKernelGGL(k_klz_a, dim3(128), dim3(256), 0, stream,
                     invA, invB, P, q_k0, q_k1);
  hipLaunchKernelGGL(k_klz_b, dim3(128), dim3(256), 0, stream,
                     t_pi, invA, invB, P, gacc, q_k0, q_k1);
  hipLaunchKernelGGL(k_wbuildT, dim3(256), dim3(256), 0, stream,
                     mW, sW, t_pi, WzT, gacc, e_k0, e_k1, u_k0, u_k1);
  hipLaunchKernelGGL(k_gemm, dim3(1024), dim3(256), 0, stream,
                     inputs, WzT, biases, out);
  hipLaunchKernelGGL(k_epi, dim3(NPART), dim3(256), 0, stream,
                     out, partial, g_k0, g_k1);
  hipLaunchKernelGGL(k_final, dim3(1), dim3(256), 0, stream,
                     gacc, partial, out + 16777216);
}

// Round 10
// 189.421 us; speedup vs baseline: 1.1506x; 1.1506x over previous
//
#include <hip/hip_runtime.h>
#include <stdint.h>
#include <math.h>

// ---------------- problem constants ----------------
#define B_N   16384
#define D_N   1024
#define K_N   512
#define KU_N  1024          // K*U
#define EPS_F 1e-8f
#define TEMP  0.67f
#define EULERC 0.5772156649015329f

#define HEPS  524288        // 2^19  (eps stream half)
#define HU    262144        // 2^18  (bernoulli/kumaraswamy stream half)
#define HG    8388608       // 2^23  (gumbel stream half)

typedef uint32_t u32;
typedef __attribute__((ext_vector_type(4))) float f32x4;
typedef __attribute__((ext_vector_type(4))) unsigned int u32x4;
typedef __attribute__((ext_vector_type(8))) __bf16 bf16x8;

// ---------------- threefry2x32 (JAX-exact) ----------------
#define TF_ROT(x, r) (((x) << (r)) | ((x) >> (32 - (r))))

__host__ __device__ static inline void threefry2x32(u32 k0, u32 k1,
                                                    u32 x0, u32 x1,
                                                    u32* o0, u32* o1) {
  u32 ks2 = k0 ^ k1 ^ 0x1BD11BDAu;
  x0 += k0; x1 += k1;
  x0 += x1; x1 = TF_ROT(x1, 13); x1 ^= x0;
  x0 += x1; x1 = TF_ROT(x1, 15); x1 ^= x0;
  x0 += x1; x1 = TF_ROT(x1, 26); x1 ^= x0;
  x0 += x1; x1 = TF_ROT(x1, 6);  x1 ^= x0;
  x0 += k1; x1 += ks2 + 1u;
  x0 += x1; x1 = TF_ROT(x1, 17); x1 ^= x0;
  x0 += x1; x1 = TF_ROT(x1, 29); x1 ^= x0;
  x0 += x1; x1 = TF_ROT(x1, 16); x1 ^= x0;
  x0 += x1; x1 = TF_ROT(x1, 24); x1 ^= x0;
  x0 += ks2; x1 += k0 + 2u;
  x0 += x1; x1 = TF_ROT(x1, 13); x1 ^= x0;
  x0 += x1; x1 = TF_ROT(x1, 15); x1 ^= x0;
  x0 += x1; x1 = TF_ROT(x1, 26); x1 ^= x0;
  x0 += x1; x1 = TF_ROT(x1, 6);  x1 ^= x0;
  x0 += k0; x1 += k1 + 3u;
  x0 += x1; x1 = TF_ROT(x1, 17); x1 ^= x0;
  x0 += x1; x1 = TF_ROT(x1, 29); x1 ^= x0;
  x0 += x1; x1 = TF_ROT(x1, 16); x1 ^= x0;
  x0 += x1; x1 = TF_ROT(x1, 24); x1 ^= x0;
  x0 += k1; x1 += ks2 + 4u;
  x0 += x1; x1 = TF_ROT(x1, 13); x1 ^= x0;
  x0 += x1; x1 = TF_ROT(x1, 15); x1 ^= x0;
  x0 += x1; x1 = TF_ROT(x1, 26); x1 ^= x0;
  x0 += x1; x1 = TF_ROT(x1, 6);  x1 ^= x0;
  x0 += ks2; x1 += k0 + 5u;
  *o0 = x0; *o1 = x1;
}

// ---------------- numeric helpers ----------------
__device__ static inline float bits_to_u01(u32 b) {
  u32 f = (b >> 9) | 0x3f800000u;
  return __uint_as_float(f) - 1.0f;
}
__device__ static inline float unif_f(u32 b, float lo, float hi) {
  float f = bits_to_u01(b);
  return fmaxf(lo, f * (hi - lo) + lo);
}
__device__ static inline float erfinv_f(float x) {
  float w = -log1pf(-x * x);
  float p;
  if (w < 5.f) {
    w -= 2.5f;
    p = 2.81022636e-08f;
    p = fmaf(p, w, 3.43273939e-07f);
    p = fmaf(p, w, -3.5233877e-06f);
    p = fmaf(p, w, -4.39150654e-06f);
    p = fmaf(p, w, 0.00021858087f);
    p = fmaf(p, w, -0.00125372503f);
    p = fmaf(p, w, -0.00417768164f);
    p = fmaf(p, w, 0.246640727f);
    p = fmaf(p, w, 1.50140941f);
  } else {
    w = sqrtf(w) - 3.f;
    p = -0.000200214257f;
    p = fmaf(p, w, 0.000100950558f);
    p = fmaf(p, w, 0.00134934322f);
    p = fmaf(p, w, -0.00367342844f);
    p = fmaf(p, w, 0.00573950773f);
    p = fmaf(p, w, -0.0076224613f);
    p = fmaf(p, w, 0.00943887047f);
    p = fmaf(p, w, 1.00167406f);
    p = fmaf(p, w, 2.83297682f);
  }
  return p * x;
}
__device__ static inline float softplus_f(float x) {
  return fmaxf(x, 0.f) + log1pf(expf(-fabsf(x)));
}
__device__ static inline float rcp_f(float x) { return __builtin_amdgcn_rcpf(x); }
__device__ static inline float sigmoid_fast(float x) {
  return rcp_f(1.f + __expf(-x));
}
__device__ static inline float digamma_f(float x) {
  float r = 0.f;
  while (x < 6.f) { r -= 1.f / x; x += 1.f; }
  float inv = 1.f / x, inv2 = inv * inv;
  return r + logf(x) - 0.5f * inv
       - inv2 * (1.f / 12.f - inv2 * (1.f / 120.f - inv2 * (1.f / 252.f)));
}
__device__ static inline unsigned short f2bf_rne(float x) {
  u32 u = __float_as_uint(x);
  u32 r = (u + 0x7fffu + ((u >> 16) & 1u)) >> 16;
  return (unsigned short)r;
}
__device__ static inline u32 cvt_pk_bf16(float lo, float hi) {
  u32 r;
  asm("v_cvt_pk_bf16_f32 %0, %1, %2" : "=v"(r) : "v"(lo), "v"(hi));
  return r;
}
__device__ static inline void gload_lds16(const void* g, void* l) {
  __builtin_amdgcn_global_load_lds(
      (const __attribute__((address_space(1))) u32*)g,
      (__attribute__((address_space(3))) u32*)l, 16, 0, 0);
}

// block-wide sum; valid result only on thread 0
__device__ static inline float block_sum(float v) {
  __shared__ float sm[16];
  int lane = threadIdx.x & 63;
  int wid = threadIdx.x >> 6;
  #pragma unroll
  for (int o = 32; o > 0; o >>= 1) v += __shfl_down(v, o, 64);
  if (lane == 0) sm[wid] = v;
  __syncthreads();
  float s = 0.f;
  if (threadIdx.x == 0) {
    int nw = (blockDim.x + 63) >> 6;
    s = sm[0];
    for (int w = 1; w < nw; ++w) s += sm[w];
  }
  return s;
}

// ---------------- kernels ----------------
// init: per-k tables, kl_sticks -> gacc[1], zero gacc[0], gacc[2]
__global__ void k_init(const float* __restrict__ conc1,
                       const float* __restrict__ conc0,
                       float* __restrict__ invA, float* __restrict__ invB,
                       float* gacc) {
  int k = threadIdx.x;  // 512
  float a = softplus_f(conc1[k]);
  float b = softplus_f(conc0[k]);
  invA[k] = 1.f / a;
  invB[k] = 1.f / b;
  float s = ((a - 1.f) / a) * (-EULERC - digamma_f(b) - 1.f / b)
          + logf(a * b + EPS_F) - (b - 1.f) / b;
  float t = block_sum(s);
  if (threadIdx.x == 0) { gacc[0] = 0.f; gacc[1] = t; gacc[2] = 0.f; }
}

// kl_z pass A: 64 chunks of 16 d's; qu computed inline (threefry + pow)
__global__ __launch_bounds__(256) void k_klz_a(const float* __restrict__ invA,
                                               const float* __restrict__ invB,
                                               float* __restrict__ P,
                                               u32 qk0, u32 qk1) {
  int idx = blockIdx.x * 256 + threadIdx.x;  // [0, 32768)
  int c = idx >> 9, k = idx & (K_N - 1);
  float iA = invA[k], iB = invB[k];
  float p = 1.f;
  int d0 = c << 4;
  for (int d = d0; d < d0 + 16; ++d) {
    int n = (d << 9) + k;
    u32 x0 = (n < HU) ? (u32)n : (u32)(n - HU);
    u32 o0, o1;
    threefry2x32(qk0, qk1, x0, x0 + HU, &o0, &o1);
    u32 bits = (n < HU) ? o0 : o1;
    float u = unif_f(bits, 1e-6f, 1.f - 1e-6f);
    p *= powf(1.f - powf(u, iB), iA);
  }
  P[idx] = p;
}

// kl_z pass B: prefix-recombined cumprod + KL sum -> atomicAdd gacc[1]
__global__ __launch_bounds__(256) void k_klz_b(const float* __restrict__ t_pi,
                                               const float* __restrict__ invA,
                                               const float* __restrict__ invB,
                                               const float* __restrict__ P,
                                               float* gacc,
                                               u32 qk0, u32 qk1) {
  int idx = blockIdx.x * 256 + threadIdx.x;  // [0, 32768)
  int c = idx >> 9, k = idx & (K_N - 1);
  float iA = invA[k], iB = invB[k];
  float prior = 1.f;
  for (int c2 = 0; c2 < c; ++c2) prior *= P[(c2 << 9) + k];
  float s = 0.f;
  int d0 = c << 4;
  for (int d = d0; d < d0 + 16; ++d) {
    int n = (d << 9) + k;
    u32 x0 = (n < HU) ? (u32)n : (u32)(n - HU);
    u32 o0, o1;
    threefry2x32(qk0, qk1, x0, x0 + HU, &o0, &o1);
    u32 bits = (n < HU) ? o0 : o1;
    float u = unif_f(bits, 1e-6f, 1.f - 1e-6f);
    prior *= powf(1.f - powf(u, iB), iA);
    float q = sigmoid_fast(t_pi[n]);
    s += q * (__logf(q + EPS_F) - __logf(prior + EPS_F));
  }
  float t = block_sum(s);
  if (threadIdx.x == 0) atomicAdd(&gacc[1], t);
}

// WzT[j][d] = z(d, j%K)*(mW[d][j]+eps*softplus(sW[d][j])) in bf16, via 64x64
// LDS transpose tile (coalesced loads AND stores); kl_weights -> gacc[0]
__global__ __launch_bounds__(256) void k_wbuildT(const float* __restrict__ mW,
                                                 const float* __restrict__ sW,
                                                 const float* __restrict__ t_pi,
                                                 unsigned short* __restrict__ WzT,
                                                 float* __restrict__ gacc,
                                                 u32 ek0, u32 ek1,
                                                 u32 uk0, u32 uk1) {
  __shared__ unsigned short tile[64][65];
  int dt = (int)blockIdx.x >> 4;   // 0..15
  int jt = (int)blockIdx.x & 15;   // 0..15
  int d0 = dt << 6, j0 = jt << 6;
  int tj = threadIdx.x & 63;
  int tr = threadIdx.x >> 6;       // 0..3
  int j = j0 + tj;
  int kk = j & (K_N - 1);
  bool lowD = (dt < 8);
  float klw = 0.f;
  #pragma unroll 4
  for (int rr = 0; rr < 16; ++rr) {
    int dl = (rr << 2) + tr;
    int d = d0 + dl;
    int n = (d << 10) + j;
    u32 x0 = lowD ? (u32)n : (u32)(n - HEPS);
    u32 o0, o1;
    threefry2x32(ek0, ek1, x0, x0 + HEPS, &o0, &o1);
    u32 ebits = lowD ? o0 : o1;
    int nz = (d << 9) + kk;
    u32 zx0 = lowD ? (u32)nz : (u32)(nz - HU);
    u32 z0, z1;
    threefry2x32(uk0, uk1, zx0, zx0 + HU, &z0, &z1);
    u32 zbits = lowD ? z0 : z1;
    float u = unif_f(zbits, 1e-6f, 1.f - 1e-6f);
    float logistic = __logf(u) - log1pf(-u);
    float z = sigmoid_fast((t_pi[nz] + logistic) * (1.f / TEMP));
    float un = unif_f(ebits, -0.99999994f, 1.0f);
    float epsn = 1.41421356f * erfinv_f(un);
    float m = mW[n], sp = softplus_f(sW[n]);
    tile[tj][dl] = f2bf_rne(z * (m + epsn * sp));
    klw += 2.f * sp - m * m - sp * sp + 1.f;
  }
  __syncthreads();
  #pragma unroll 4
  for (int rr = 0; rr < 16; ++rr) {
    int jl = (rr << 2) + tr;
    WzT[(size_t)(j0 + jl) * D_N + d0 + tj] = tile[jl][tj];
  }
  float t = block_sum(klw);
  if (threadIdx.x == 0) atomicAdd(&gacc[0], t);
}

// ---------------- MFMA GEMM: C[b][j] = sum_d A[b][d]*WzT[j][d] + bias[j] ----
// 256x256 tile, 512 threads = 8 waves (2M x 4N), BK=64, double-buffered
// 128KB LDS, raw s_barrier + counted vmcnt(8). Per-wave barrier invariant:
// outstanding vmem = [B(t+1)x4 oldest, A-regs(t+2)x8 newest] -> vmcnt(8)
// retires exactly this wave's 4 B-gloads. grid = 64x4 = 256 blocks = 1/CU.
#define TBM 256
#define TBN 256
#define TBK 64

__global__ __launch_bounds__(512, 2) void k_gemm(const float* __restrict__ A,
                                                 const unsigned short* __restrict__ Bt,
                                                 const float* __restrict__ bias,
                                                 float* __restrict__ C) {
  __shared__ __align__(16) unsigned short As[2][TBM * TBK];  // 32KB each
  __shared__ __align__(16) unsigned short Bs[2][TBN * TBK];  // 32KB each

  // XCD-chunked swizzle (256 blocks, 32 per XCD)
  int f = (int)blockIdx.x;
  int wk = (f & 7) * 32 + (f >> 3);
  const int brow = (wk >> 2) * TBM;          // 64 M-tiles
  const int bcol = (wk & 3) * TBN;           // 4 N-tiles

  const int tid = threadIdx.x;
  const int lane = tid & 63;
  const int w = tid >> 6;                    // 0..7

  // A reg-staging: thread t covers row t>>1, f32 cols (t&1)*32 + 0..31
  const int ar = tid >> 1;
  const float* gA = A + (size_t)(brow + ar) * D_N + ((tid & 1) << 5);
  const int cb = (tid & 1) << 2;             // chunk base 0 or 4
  int aoff[4];
  #pragma unroll
  for (int i = 0; i < 4; ++i)
    aoff[i] = (ar << 7) + (((cb + i) ^ (ar & 7)) << 4);

  // B staging: issue q covers cols q*64 + (tid>>3); chunk tid&7 pre-swizzled
  const int bcl = tid >> 3;                  // 0..63
  const unsigned short* gB = Bt + (size_t)(bcol + bcl) * D_N
                           + (((tid & 7) ^ (bcl & 7)) << 3);
  const int bdst = (w << 10);                // + q*8192 per issue

  f32x4 acc[8][4];
  #pragma unroll
  for (int m = 0; m < 8; ++m)
    #pragma unroll
    for (int n = 0; n < 4; ++n) acc[m][n] = (f32x4){0.f, 0.f, 0.f, 0.f};

  const int wrow = (w >> 2) << 7;   // 0 or 128
  const int wcol = (w & 3) << 6;    // 0,64,128,192
  const int fr = lane & 15;
  const int kg = lane >> 4;         // 0..3

  f32x4 av[8];

  // ---- prologue: A-regs(0); gloadB(0)->buf0; pack A(0)->buf0; A-regs(1)
  #pragma unroll
  for (int j = 0; j < 8; ++j) av[j] = *(const f32x4*)(gA + (j << 2));
  #pragma unroll
  for (int q = 0; q < 4; ++q)
    gload_lds16(gB + (size_t)(q * 64) * D_N, (char*)Bs[0] + q * 8192 + bdst);
  __builtin_amdgcn_sched_barrier(0);
  #pragma unroll
  for (int i = 0; i < 4; ++i) {
    u32x4 p;
    p.x = cvt_pk_bf16(av[2 * i].x, av[2 * i].y);
    p.y = cvt_pk_bf16(av[2 * i].z, av[2 * i].w);
    p.z = cvt_pk_bf16(av[2 * i + 1].x, av[2 * i + 1].y);
    p.w = cvt_pk_bf16(av[2 * i + 1].z, av[2 * i + 1].w);
    *(u32x4*)((char*)As[0] + aoff[i]) = p;
  }
  #pragma unroll
  for (int j = 0; j < 8; ++j) av[j] = *(const f32x4*)(gA + TBK + (j << 2));
  asm volatile("s_waitcnt vmcnt(8) lgkmcnt(0)" ::: "memory");
  __builtin_amdgcn_s_barrier();

  for (int t = 0; t < 15; ++t) {
    const int cur = t & 1;
    char* curA = (char*)As + (cur << 15);
    char* curB = (char*)Bs + (cur << 15);
    char* altA = (char*)As + ((cur ^ 1) << 15);
    char* altB = (char*)Bs + ((cur ^ 1) << 15);

    // issue B(t+1) -> alt (stays in flight across this iter's barrier)
    {
      const unsigned short* gBn = gB + ((t + 1) << 6);
      #pragma unroll
      for (int q = 0; q < 4; ++q)
        gload_lds16(gBn + (size_t)(q * 64) * D_N, altB + q * 8192 + bdst);
    }
    __builtin_amdgcn_sched_barrier(0);

    // MFMA on buf[cur]: 2 k-subtiles x 32 MFMA
    __builtin_amdgcn_s_setprio(1);
    #pragma unroll
    for (int h = 0; h < 2; ++h) {
      bf16x8 af[8];
      #pragma unroll
      for (int m = 0; m < 8; ++m) {
        int row = wrow + m * 16 + fr;
        af[m] = *(const bf16x8*)(curA + (row << 7) + ((((h << 2) + kg) ^ (row & 7)) << 4));
      }
      #pragma unroll
      for (int n = 0; n < 4; ++n) {
        int col = wcol + n * 16 + fr;
        bf16x8 bf = *(const bf16x8*)(curB + (col << 7) + ((((h << 2) + kg) ^ (col & 7)) << 4));
        #pragma unroll
        for (int m = 0; m < 8; ++m)
          acc[m][n] = __builtin_amdgcn_mfma_f32_16x16x32_bf16(af[m], bf, acc[m][n], 0, 0, 0);
      }
    }
    __builtin_amdgcn_s_setprio(0);

    // pack A(t+1) (regs from iter t-1; compiler wait vmcnt(4) leaves B(t+1) in flight)
    #pragma unroll
    for (int i = 0; i < 4; ++i) {
      u32x4 p;
      p.x = cvt_pk_bf16(av[2 * i].x, av[2 * i].y);
      p.y = cvt_pk_bf16(av[2 * i].z, av[2 * i].w);
      p.z = cvt_pk_bf16(av[2 * i + 1].x, av[2 * i + 1].y);
      p.w = cvt_pk_bf16(av[2 * i + 1].z, av[2 * i + 1].w);
      *(u32x4*)(altA + aoff[i]) = p;
    }
    if (t < 14) {
      const float* g = gA + ((t + 2) << 6);
      #pragma unroll
      for (int j = 0; j < 8; ++j) av[j] = *(const f32x4*)(g + (j << 2));
    }

    asm volatile("s_waitcnt vmcnt(8) lgkmcnt(0)" ::: "memory");
    __builtin_amdgcn_s_barrier();
  }

  // tail tile 15 (buf 1): its B gloads are the youngest -> need full drain
  asm volatile("s_waitcnt vmcnt(0)" ::: "memory");
  __builtin_amdgcn_s_barrier();
  {
    char* curA = (char*)As + (1 << 15);
    char* curB = (char*)Bs + (1 << 15);
    #pragma unroll
    for (int h = 0; h < 2; ++h) {
      bf16x8 af[8];
      #pragma unroll
      for (int m = 0; m < 8; ++m) {
        int row = wrow + m * 16 + fr;
        af[m] = *(const bf16x8*)(curA + (row << 7) + ((((h << 2) + kg) ^ (row & 7)) << 4));
      }
      #pragma unroll
      for (int n = 0; n < 4; ++n) {
        int col = wcol + n * 16 + fr;
        bf16x8 bf = *(const bf16x8*)(curB + (col << 7) + ((((h << 2) + kg) ^ (col & 7)) << 4));
        #pragma unroll
        for (int m = 0; m < 8; ++m)
          acc[m][n] = __builtin_amdgcn_mfma_f32_16x16x32_bf16(af[m], bf, acc[m][n], 0, 0, 0);
      }
    }
  }

  #pragma unroll
  for (int n = 0; n < 4; ++n) {
    int col = bcol + wcol + n * 16 + fr;
    float bv = bias[col];
    #pragma unroll
    for (int m = 0; m < 8; ++m) {
      int rowb = brow + wrow + m * 16 + (kg << 2);
      C[(size_t)(rowb + 0) * KU_N + col] = acc[m][n].x + bv;
      C[(size_t)(rowb + 1) * KU_N + col] = acc[m][n].y + bv;
      C[(size_t)(rowb + 2) * KU_N + col] = acc[m][n].z + bv;
      C[(size_t)(rowb + 3) * KU_N + col] = acc[m][n].w + bv;
    }
  }
}

// ---------------- LWTA epilogue ----------------
// Minimal quad per thread: rows {b, b+8192} x cols {2k, 2k+1} share exactly
// 2 threefry hashes (all 4 outputs consumed). Small live state -> lean codegen.
__device__ static inline float lwta_pair(float v0, float v1, u32 ba, u32 bb,
                                         float* o0, float* o1) {
  float u0 = unif_f(ba, 1e-6f, 1.f - 1e-6f);
  float u1 = unif_f(bb, 1e-6f, 1.f - 1e-6f);
  float g0 = -__logf(-__logf(u0));
  float g1 = -__logf(-__logf(u1));
  const float it = 1.f / TEMP;
  float d = ((v1 + g1) - (v0 + g0)) * it;
  float xi0 = rcp_f(1.f + __expf(d));
  float xi1 = 1.f - xi0;
  *o0 = v0 * xi0;
  *o1 = v1 * xi1;
  float qd = v1 - v0;
  float q0 = rcp_f(1.f + __expf(qd));
  float q1 = 1.f - q0;
  const float LOG2F = 0.6931471805599453f;
  return q0 * (__logf(q0 + EPS_F) + LOG2F) + q1 * (__logf(q1 + EPS_F) + LOG2F);
}

__global__ __launch_bounds__(256) void k_epi(float* __restrict__ C,
                                             float* __restrict__ partial,
                                             u32 gk0, u32 gk1) {
  int idx = blockIdx.x * 256 + threadIdx.x;   // [0, 2^22)
  int b = idx >> 9;                           // 0..8191
  int c2 = (idx & 511) << 1;                  // 0,2,...,1022
  size_t p0 = (size_t)b * KU_N + c2;
  size_t p1 = p0 + (size_t)8192 * KU_N;
  float2 r0 = *(const float2*)&C[p0];
  float2 r1 = *(const float2*)&C[p1];
  u32 m = ((u32)b << 10) | (u32)c2;
  u32 x0a, x1a, x0b, x1b;
  threefry2x32(gk0, gk1, m,      m + HG,      &x0a, &x1a);
  threefry2x32(gk0, gk1, m + 1u, m + 1u + HG, &x0b, &x1b);
  float2 w0, w1;
  float kl = lwta_pair(r0.x, r0.y, x0a, x0b, &w0.x, &w0.y)
           + lwta_pair(r1.x, r1.y, x1a, x1b, &w1.x, &w1.y);
  *(float2*)&C[p0] = w0;
  *(float2*)&C[p1] = w1;
  float t = block_sum(kl);
  if (threadIdx.x == 0) partial[blockIdx.x] = t;
}

#define NPART 16384
__global__ __launch_bounds__(256) void k_final(const float* __restrict__ gacc,
                                               const float* __restrict__ partial,
                                               float* __restrict__ out_loss) {
  float s = 0.f;
  for (int i = threadIdx.x; i < NPART; i += 256) s += partial[i];
  float t = block_sum(s);
  if (threadIdx.x == 0) {
    float kl_weights = -0.5f * (gacc[0] * (1.f / 1048576.f));
    out_loss[0] = kl_weights / 60000.f + gacc[1] + t * (1.f / 32768.f);
  }
}

// ---------------- launch ----------------
extern "C" void kernel_launch(void* const* d_in, const int* in_sizes, int n_in,
                              void* d_out, int out_size, void* d_ws, size_t ws_size,
                              hipStream_t stream) {
  (void)in_sizes; (void)n_in; (void)out_size; (void)ws_size;
  const float* inputs = (const float*)d_in[0];
  const float* mW     = (const float*)d_in[1];
  const float* sW     = (const float*)d_in[2];
  const float* conc1  = (const float*)d_in[3];
  const float* conc0  = (const float*)d_in[4];
  const float* t_pi   = (const float*)d_in[5];
  const float* biases = (const float*)d_in[6];
  float* out = (float*)d_out;

  // rk[0..3] = split(key(42), 4)
  u32 a[4], b[4];
  for (int i = 0; i < 4; ++i)
    threefry2x32(0u, 42u, (u32)i, (u32)(i + 4), &a[i], &b[i]);
  u32 e_k0 = a[0], e_k1 = a[1];   // eps (normal)
  u32 u_k0 = a[2], u_k1 = a[3];   // bernoulli-u
  u32 q_k0 = b[0], q_k1 = b[1];   // kumaraswamy
  u32 g_k0 = b[2], g_k1 = b[3];   // gumbel

  char* wsb = (char*)d_ws;
  unsigned short* WzT = (unsigned short*)wsb;                   // 2MB
  float* P       = (float*)(wsb + (2u << 20));                  // 128KB
  float* invA    = (float*)(wsb + (2u << 20) + (128u << 10));   // 2KB
  float* invB    = (float*)(wsb + (2u << 20) + (130u << 10));   // 2KB
  float* gacc    = (float*)(wsb + (2u << 20) + (132u << 10));   // 32B
  float* partial = (float*)(wsb + (2u << 20) + (136u << 10));   // 64KB

  hipLaunchKernelGGL(k_init, dim3(1), dim3(512), 0, stream,
                     conc1, conc0, invA, invB, gacc);
  hipLaunchKernelGGL(k_klz_a, dim3(128), dim3(256), 0, stream,
                     invA, invB, P, q_k0, q_k1);
  hipLaunchKernelGGL(k_klz_b, dim3(128), dim3(256), 0, stream,
                     t_pi, invA, invB, P, gacc, q_k0, q_k1);
  hipLaunchKernelGGL(k_wbuildT, dim3(256), dim3(256), 0, stream,
                     mW, sW, t_pi, WzT, gacc, e_k0, e_k1, u_k0, u_k1);
  hipLaunchKernelGGL(k_gemm, dim3(256), dim3(512), 0, stream,
                     inputs, WzT, biases, out);
  hipLaunchKernelGGL(k_epi, dim3(NPART), dim3(256), 0, stream,
                     out, partial, g_k0, g_k1);
  hipLaunchKernelGGL(k_final, dim3(1), dim3(256), 0, stream,
                     gacc, partial, out + 16777216);
}

// Round 11
// 188.704 us; speedup vs baseline: 1.1550x; 1.0038x over previous
//
#include <hip/hip_runtime.h>
#include <stdint.h>
#include <math.h>

// ---------------- problem constants ----------------
#define B_N   16384
#define D_N   1024
#define K_N   512
#define KU_N  1024          // K*U
#define EPS_F 1e-8f
#define TEMP  0.67f
#define EULERC 0.5772156649015329f

#define HEPS  524288        // 2^19  (eps stream half)
#define HU    262144        // 2^18  (bernoulli/kumaraswamy stream half)
#define HG    8388608       // 2^23  (gumbel stream half)

typedef uint32_t u32;
typedef __attribute__((ext_vector_type(4))) float f32x4;
typedef __attribute__((ext_vector_type(4))) unsigned int u32x4;
typedef __attribute__((ext_vector_type(8))) __bf16 bf16x8;

// ---------------- threefry2x32 (JAX-exact) ----------------
#define TF_ROT(x, r) (((x) << (r)) | ((x) >> (32 - (r))))

__host__ __device__ static inline void threefry2x32(u32 k0, u32 k1,
                                                    u32 x0, u32 x1,
                                                    u32* o0, u32* o1) {
  u32 ks2 = k0 ^ k1 ^ 0x1BD11BDAu;
  x0 += k0; x1 += k1;
  x0 += x1; x1 = TF_ROT(x1, 13); x1 ^= x0;
  x0 += x1; x1 = TF_ROT(x1, 15); x1 ^= x0;
  x0 += x1; x1 = TF_ROT(x1, 26); x1 ^= x0;
  x0 += x1; x1 = TF_ROT(x1, 6);  x1 ^= x0;
  x0 += k1; x1 += ks2 + 1u;
  x0 += x1; x1 = TF_ROT(x1, 17); x1 ^= x0;
  x0 += x1; x1 = TF_ROT(x1, 29); x1 ^= x0;
  x0 += x1; x1 = TF_ROT(x1, 16); x1 ^= x0;
  x0 += x1; x1 = TF_ROT(x1, 24); x1 ^= x0;
  x0 += ks2; x1 += k0 + 2u;
  x0 += x1; x1 = TF_ROT(x1, 13); x1 ^= x0;
  x0 += x1; x1 = TF_ROT(x1, 15); x1 ^= x0;
  x0 += x1; x1 = TF_ROT(x1, 26); x1 ^= x0;
  x0 += x1; x1 = TF_ROT(x1, 6);  x1 ^= x0;
  x0 += k0; x1 += k1 + 3u;
  x0 += x1; x1 = TF_ROT(x1, 17); x1 ^= x0;
  x0 += x1; x1 = TF_ROT(x1, 29); x1 ^= x0;
  x0 += x1; x1 = TF_ROT(x1, 16); x1 ^= x0;
  x0 += x1; x1 = TF_ROT(x1, 24); x1 ^= x0;
  x0 += k1; x1 += ks2 + 4u;
  x0 += x1; x1 = TF_ROT(x1, 13); x1 ^= x0;
  x0 += x1; x1 = TF_ROT(x1, 15); x1 ^= x0;
  x0 += x1; x1 = TF_ROT(x1, 26); x1 ^= x0;
  x0 += x1; x1 = TF_ROT(x1, 6);  x1 ^= x0;
  x0 += ks2; x1 += k0 + 5u;
  *o0 = x0; *o1 = x1;
}

// ---------------- numeric helpers ----------------
__device__ static inline float bits_to_u01(u32 b) {
  u32 f = (b >> 9) | 0x3f800000u;
  return __uint_as_float(f) - 1.0f;
}
__device__ static inline float unif_f(u32 b, float lo, float hi) {
  float f = bits_to_u01(b);
  return fmaxf(lo, f * (hi - lo) + lo);
}
__device__ static inline float erfinv_f(float x) {
  float w = -log1pf(-x * x);
  float p;
  if (w < 5.f) {
    w -= 2.5f;
    p = 2.81022636e-08f;
    p = fmaf(p, w, 3.43273939e-07f);
    p = fmaf(p, w, -3.5233877e-06f);
    p = fmaf(p, w, -4.39150654e-06f);
    p = fmaf(p, w, 0.00021858087f);
    p = fmaf(p, w, -0.00125372503f);
    p = fmaf(p, w, -0.00417768164f);
    p = fmaf(p, w, 0.246640727f);
    p = fmaf(p, w, 1.50140941f);
  } else {
    w = sqrtf(w) - 3.f;
    p = -0.000200214257f;
    p = fmaf(p, w, 0.000100950558f);
    p = fmaf(p, w, 0.00134934322f);
    p = fmaf(p, w, -0.00367342844f);
    p = fmaf(p, w, 0.00573950773f);
    p = fmaf(p, w, -0.0076224613f);
    p = fmaf(p, w, 0.00943887047f);
    p = fmaf(p, w, 1.00167406f);
    p = fmaf(p, w, 2.83297682f);
  }
  return p * x;
}
__device__ static inline float softplus_f(float x) {
  return fmaxf(x, 0.f) + log1pf(expf(-fabsf(x)));
}
__device__ static inline float rcp_f(float x) { return __builtin_amdgcn_rcpf(x); }
__device__ static inline float sigmoid_fast(float x) {
  return rcp_f(1.f + __expf(-x));
}
__device__ static inline float digamma_f(float x) {
  float r = 0.f;
  while (x < 6.f) { r -= 1.f / x; x += 1.f; }
  float inv = 1.f / x, inv2 = inv * inv;
  return r + logf(x) - 0.5f * inv
       - inv2 * (1.f / 12.f - inv2 * (1.f / 120.f - inv2 * (1.f / 252.f)));
}
__device__ static inline unsigned short f2bf_rne(float x) {
  u32 u = __float_as_uint(x);
  u32 r = (u + 0x7fffu + ((u >> 16) & 1u)) >> 16;
  return (unsigned short)r;
}
__device__ static inline u32 cvt_pk_bf16(float lo, float hi) {
  u32 r;
  asm("v_cvt_pk_bf16_f32 %0, %1, %2" : "=v"(r) : "v"(lo), "v"(hi));
  return r;
}
__device__ static inline void gload_lds16(const void* g, void* l) {
  __builtin_amdgcn_global_load_lds(
      (const __attribute__((address_space(1))) u32*)g,
      (__attribute__((address_space(3))) u32*)l, 16, 0, 0);
}

// block-wide sum; valid result only on thread 0
__device__ static inline float block_sum(float v) {
  __shared__ float sm[16];
  int lane = threadIdx.x & 63;
  int wid = threadIdx.x >> 6;
  #pragma unroll
  for (int o = 32; o > 0; o >>= 1) v += __shfl_down(v, o, 64);
  if (lane == 0) sm[wid] = v;
  __syncthreads();
  float s = 0.f;
  if (threadIdx.x == 0) {
    int nw = (blockDim.x + 63) >> 6;
    s = sm[0];
    for (int w = 1; w < nw; ++w) s += sm[w];
  }
  return s;
}

// ---------------- kernels ----------------
// kl_z pass A: 64 chunks of 16 d's; qu computed inline (threefry + pow)
__global__ __launch_bounds__(256) void k_klz_a(const float* __restrict__ conc1,
                                               const float* __restrict__ conc0,
                                               float* __restrict__ P,
                                               u32 qk0, u32 qk1) {
  int idx = blockIdx.x * 256 + threadIdx.x;  // [0, 32768)
  int c = idx >> 9, k = idx & (K_N - 1);
  float iA = 1.f / softplus_f(conc1[k]);
  float iB = 1.f / softplus_f(conc0[k]);
  float p = 1.f;
  int d0 = c << 4;
  for (int d = d0; d < d0 + 16; ++d) {
    int n = (d << 9) + k;
    u32 x0 = (n < HU) ? (u32)n : (u32)(n - HU);
    u32 o0, o1;
    threefry2x32(qk0, qk1, x0, x0 + HU, &o0, &o1);
    u32 bits = (n < HU) ? o0 : o1;
    float u = unif_f(bits, 1e-6f, 1.f - 1e-6f);
    p *= powf(1.f - powf(u, iB), iA);
  }
  P[idx] = p;
}

// kl_z pass B: prefix-recombined cumprod + KL sum -> per-block partialZ
__global__ __launch_bounds__(256) void k_klz_b(const float* __restrict__ t_pi,
                                               const float* __restrict__ conc1,
                                               const float* __restrict__ conc0,
                                               const float* __restrict__ P,
                                               float* __restrict__ partialZ,
                                               u32 qk0, u32 qk1) {
  int idx = blockIdx.x * 256 + threadIdx.x;  // [0, 32768)
  int c = idx >> 9, k = idx & (K_N - 1);
  float iA = 1.f / softplus_f(conc1[k]);
  float iB = 1.f / softplus_f(conc0[k]);
  float prior = 1.f;
  for (int c2 = 0; c2 < c; ++c2) prior *= P[(c2 << 9) + k];
  float s = 0.f;
  int d0 = c << 4;
  for (int d = d0; d < d0 + 16; ++d) {
    int n = (d << 9) + k;
    u32 x0 = (n < HU) ? (u32)n : (u32)(n - HU);
    u32 o0, o1;
    threefry2x32(qk0, qk1, x0, x0 + HU, &o0, &o1);
    u32 bits = (n < HU) ? o0 : o1;
    float u = unif_f(bits, 1e-6f, 1.f - 1e-6f);
    prior *= powf(1.f - powf(u, iB), iA);
    float q = sigmoid_fast(t_pi[n]);
    s += q * (__logf(q + EPS_F) - __logf(prior + EPS_F));
  }
  float t = block_sum(s);
  if (threadIdx.x == 0) partialZ[blockIdx.x] = t;
}

// WzT[j][d] = z(d, j%K)*(mW[d][j]+eps*softplus(sW[d][j])) in bf16, via 64x64
// LDS transpose tile (coalesced loads AND stores); kl_weights -> partialW
__global__ __launch_bounds__(256) void k_wbuildT(const float* __restrict__ mW,
                                                 const float* __restrict__ sW,
                                                 const float* __restrict__ t_pi,
                                                 unsigned short* __restrict__ WzT,
                                                 float* __restrict__ partialW,
                                                 u32 ek0, u32 ek1,
                                                 u32 uk0, u32 uk1) {
  __shared__ unsigned short tile[64][65];
  int dt = (int)blockIdx.x >> 4;   // 0..15
  int jt = (int)blockIdx.x & 15;   // 0..15
  int d0 = dt << 6, j0 = jt << 6;
  int tj = threadIdx.x & 63;
  int tr = threadIdx.x >> 6;       // 0..3
  int j = j0 + tj;
  int kk = j & (K_N - 1);
  bool lowD = (dt < 8);
  float klw = 0.f;
  #pragma unroll 4
  for (int rr = 0; rr < 16; ++rr) {
    int dl = (rr << 2) + tr;
    int d = d0 + dl;
    int n = (d << 10) + j;
    u32 x0 = lowD ? (u32)n : (u32)(n - HEPS);
    u32 o0, o1;
    threefry2x32(ek0, ek1, x0, x0 + HEPS, &o0, &o1);
    u32 ebits = lowD ? o0 : o1;
    int nz = (d << 9) + kk;
    u32 zx0 = lowD ? (u32)nz : (u32)(nz - HU);
    u32 z0, z1;
    threefry2x32(uk0, uk1, zx0, zx0 + HU, &z0, &z1);
    u32 zbits = lowD ? z0 : z1;
    float u = unif_f(zbits, 1e-6f, 1.f - 1e-6f);
    float logistic = __logf(u) - log1pf(-u);
    float z = sigmoid_fast((t_pi[nz] + logistic) * (1.f / TEMP));
    float un = unif_f(ebits, -0.99999994f, 1.0f);
    float epsn = 1.41421356f * erfinv_f(un);
    float m = mW[n], sp = softplus_f(sW[n]);
    tile[tj][dl] = f2bf_rne(z * (m + epsn * sp));
    klw += 2.f * sp - m * m - sp * sp + 1.f;
  }
  __syncthreads();
  #pragma unroll 4
  for (int rr = 0; rr < 16; ++rr) {
    int jl = (rr << 2) + tr;
    WzT[(size_t)(j0 + jl) * D_N + d0 + tj] = tile[jl][tj];
  }
  float t = block_sum(klw);
  if (threadIdx.x == 0) partialW[blockIdx.x] = t;
}

// ---------------- MFMA GEMM: C[b][j] = sum_d A[b][d]*WzT[j][d] + bias[j] ----
// 256x256 tile, 512 threads = 8 waves (2M x 4N), BK=64, double-buffered
// 128KB LDS. Each K-step split into 2 phases (T3): per phase {issue 2
// B-gloads, ds_read af subtile, s_barrier, setprio+32 MFMA, s_barrier}.
// One counted vmcnt(8)+lgkmcnt(0) per K-step: A-regs(t+2)x8 stay in flight,
// B(t+1)x4 retire, A-pack ds_writes drained for the cross-wave handoff.
#define TBM 256
#define TBN 256
#define TBK 64

__global__ __launch_bounds__(512, 2) void k_gemm(const float* __restrict__ A,
                                                 const unsigned short* __restrict__ Bt,
                                                 const float* __restrict__ bias,
                                                 float* __restrict__ C) {
  __shared__ __align__(16) unsigned short As[2][TBM * TBK];  // 32KB each
  __shared__ __align__(16) unsigned short Bs[2][TBN * TBK];  // 32KB each

  // XCD-chunked swizzle (256 blocks, 32 per XCD)
  int f = (int)blockIdx.x;
  int wk = (f & 7) * 32 + (f >> 3);
  const int brow = (wk >> 2) * TBM;          // 64 M-tiles
  const int bcol = (wk & 3) * TBN;           // 4 N-tiles

  const int tid = threadIdx.x;
  const int lane = tid & 63;
  const int w = tid >> 6;                    // 0..7

  // A reg-staging: thread t covers row t>>1, f32 cols (t&1)*32 + 0..31
  const int ar = tid >> 1;
  const float* gA = A + (size_t)(brow + ar) * D_N + ((tid & 1) << 5);
  const int cb = (tid & 1) << 2;             // chunk base 0 or 4
  int aoff[4];
  #pragma unroll
  for (int i = 0; i < 4; ++i)
    aoff[i] = (ar << 7) + (((cb + i) ^ (ar & 7)) << 4);

  // B staging: issue q covers cols q*64 + (tid>>3); chunk tid&7 pre-swizzled
  const int bcl = tid >> 3;                  // 0..63
  const unsigned short* gB = Bt + (size_t)(bcol + bcl) * D_N
                           + (((tid & 7) ^ (bcl & 7)) << 3);
  const int bdst = (w << 10);                // + q*8192 per issue

  f32x4 acc[8][4];
  #pragma unroll
  for (int m = 0; m < 8; ++m)
    #pragma unroll
    for (int n = 0; n < 4; ++n) acc[m][n] = (f32x4){0.f, 0.f, 0.f, 0.f};

  const int wrow = (w >> 2) << 7;   // 0 or 128
  const int wcol = (w & 3) << 6;    // 0,64,128,192
  const int fr = lane & 15;
  const int kg = lane >> 4;         // 0..3

  f32x4 av[8];

  // ---- prologue: A-regs(0); gloadB(0)->buf0; pack A(0)->buf0; A-regs(1)
  #pragma unroll
  for (int j = 0; j < 8; ++j) av[j] = *(const f32x4*)(gA + (j << 2));
  #pragma unroll
  for (int q = 0; q < 4; ++q)
    gload_lds16(gB + (size_t)(q * 64) * D_N, (char*)Bs[0] + q * 8192 + bdst);
  __builtin_amdgcn_sched_barrier(0);
  #pragma unroll
  for (int i = 0; i < 4; ++i) {
    u32x4 p;
    p.x = cvt_pk_bf16(av[2 * i].x, av[2 * i].y);
    p.y = cvt_pk_bf16(av[2 * i].z, av[2 * i].w);
    p.z = cvt_pk_bf16(av[2 * i + 1].x, av[2 * i + 1].y);
    p.w = cvt_pk_bf16(av[2 * i + 1].z, av[2 * i + 1].w);
    *(u32x4*)((char*)As[0] + aoff[i]) = p;
  }
  #pragma unroll
  for (int j = 0; j < 8; ++j) av[j] = *(const f32x4*)(gA + TBK + (j << 2));
  asm volatile("s_waitcnt vmcnt(8) lgkmcnt(0)" ::: "memory");
  __builtin_amdgcn_s_barrier();

  for (int t = 0; t < 15; ++t) {
    const int cur = t & 1;
    char* curA = (char*)As + (cur << 15);
    char* curB = (char*)Bs + (cur << 15);
    char* altA = (char*)As + ((cur ^ 1) << 15);
    char* altB = (char*)Bs + ((cur ^ 1) << 15);
    const unsigned short* gBn = gB + ((t + 1) << 6);

    // ======== phase 0 (k-half 0) ========
    gload_lds16(gBn + (size_t)(0 * 64) * D_N, altB + 0 * 8192 + bdst);
    gload_lds16(gBn + (size_t)(1 * 64) * D_N, altB + 1 * 8192 + bdst);
    bf16x8 af0[8];
    #pragma unroll
    for (int m = 0; m < 8; ++m) {
      int row = wrow + m * 16 + fr;
      af0[m] = *(const bf16x8*)(curA + (row << 7) + ((kg ^ (row & 7)) << 4));
    }
    __builtin_amdgcn_sched_barrier(0);
    __builtin_amdgcn_s_barrier();
    __builtin_amdgcn_sched_barrier(0);
    __builtin_amdgcn_s_setprio(1);
    #pragma unroll
    for (int n = 0; n < 4; ++n) {
      int col = wcol + n * 16 + fr;
      bf16x8 bf = *(const bf16x8*)(curB + (col << 7) + ((kg ^ (col & 7)) << 4));
      #pragma unroll
      for (int m = 0; m < 8; ++m)
        acc[m][n] = __builtin_amdgcn_mfma_f32_16x16x32_bf16(af0[m], bf, acc[m][n], 0, 0, 0);
    }
    __builtin_amdgcn_s_setprio(0);
    __builtin_amdgcn_sched_barrier(0);
    __builtin_amdgcn_s_barrier();

    // ======== phase 1 (k-half 1) ========
    gload_lds16(gBn + (size_t)(2 * 64) * D_N, altB + 2 * 8192 + bdst);
    gload_lds16(gBn + (size_t)(3 * 64) * D_N, altB + 3 * 8192 + bdst);
    bf16x8 af1[8];
    #pragma unroll
    for (int m = 0; m < 8; ++m) {
      int row = wrow + m * 16 + fr;
      af1[m] = *(const bf16x8*)(curA + (row << 7) + (((4 + kg) ^ (row & 7)) << 4));
    }
    // pack A(t+1) into alt (regs from iter t-1; the compiler's vmcnt wait for
    // av leaves the just-issued B(t+1) gloads in flight)
    #pragma unroll
    for (int i = 0; i < 4; ++i) {
      u32x4 p;
      p.x = cvt_pk_bf16(av[2 * i].x, av[2 * i].y);
      p.y = cvt_pk_bf16(av[2 * i].z, av[2 * i].w);
      p.z = cvt_pk_bf16(av[2 * i + 1].x, av[2 * i + 1].y);
      p.w = cvt_pk_bf16(av[2 * i + 1].z, av[2 * i + 1].w);
      *(u32x4*)(altA + aoff[i]) = p;
    }
    if (t < 14) {
      const float* g = gA + ((t + 2) << 6);
      #pragma unroll
      for (int j = 0; j < 8; ++j) av[j] = *(const f32x4*)(g + (j << 2));
    }
    __builtin_amdgcn_sched_barrier(0);
    __builtin_amdgcn_s_barrier();
    __builtin_amdgcn_sched_barrier(0);
    __builtin_amdgcn_s_setprio(1);
    #pragma unroll
    for (int n = 0; n < 4; ++n) {
      int col = wcol + n * 16 + fr;
      bf16x8 bf = *(const bf16x8*)(curB + (col << 7) + (((4 + kg) ^ (col & 7)) << 4));
      #pragma unroll
      for (int m = 0; m < 8; ++m)
        acc[m][n] = __builtin_amdgcn_mfma_f32_16x16x32_bf16(af1[m], bf, acc[m][n], 0, 0, 0);
    }
    __builtin_amdgcn_s_setprio(0);
    // iter-end: retire B(t+1)x4 (oldest), keep A(t+2)x8 in flight; drain
    // lgkm so the A-pack ds_writes are visible to all waves after barrier
    asm volatile("s_waitcnt vmcnt(8) lgkmcnt(0)" ::: "memory");
    __builtin_amdgcn_s_barrier();
  }

  // tail tile 15 (buf 1): its B gloads are the youngest -> full drain
  asm volatile("s_waitcnt vmcnt(0)" ::: "memory");
  __builtin_amdgcn_s_barrier();
  {
    char* curA = (char*)As + (1 << 15);
    char* curB = (char*)Bs + (1 << 15);
    #pragma unroll
    for (int h = 0; h < 2; ++h) {
      bf16x8 af[8];
      #pragma unroll
      for (int m = 0; m < 8; ++m) {
        int row = wrow + m * 16 + fr;
        af[m] = *(const bf16x8*)(curA + (row << 7) + ((((h << 2) + kg) ^ (row & 7)) << 4));
      }
      #pragma unroll
      for (int n = 0; n < 4; ++n) {
        int col = wcol + n * 16 + fr;
        bf16x8 bf = *(const bf16x8*)(curB + (col << 7) + ((((h << 2) + kg) ^ (col & 7)) << 4));
        #pragma unroll
        for (int m = 0; m < 8; ++m)
          acc[m][n] = __builtin_amdgcn_mfma_f32_16x16x32_bf16(af[m], bf, acc[m][n], 0, 0, 0);
      }
    }
  }

  #pragma unroll
  for (int n = 0; n < 4; ++n) {
    int col = bcol + wcol + n * 16 + fr;
    float bv = bias[col];
    #pragma unroll
    for (int m = 0; m < 8; ++m) {
      int rowb = brow + wrow + m * 16 + (kg << 2);
      C[(size_t)(rowb + 0) * KU_N + col] = acc[m][n].x + bv;
      C[(size_t)(rowb + 1) * KU_N + col] = acc[m][n].y + bv;
      C[(size_t)(rowb + 2) * KU_N + col] = acc[m][n].z + bv;
      C[(size_t)(rowb + 3) * KU_N + col] = acc[m][n].w + bv;
    }
  }
}

// ---------------- LWTA epilogue ----------------
// Minimal quad per thread: rows {b, b+8192} x cols {2k, 2k+1} share exactly
// 2 threefry hashes (all 4 outputs consumed). Small live state -> lean codegen.
__device__ static inline float lwta_pair(float v0, float v1, u32 ba, u32 bb,
                                         float* o0, float* o1) {
  float u0 = unif_f(ba, 1e-6f, 1.f - 1e-6f);
  float u1 = unif_f(bb, 1e-6f, 1.f - 1e-6f);
  float g0 = -__logf(-__logf(u0));
  float g1 = -__logf(-__logf(u1));
  const float it = 1.f / TEMP;
  float d = ((v1 + g1) - (v0 + g0)) * it;
  float xi0 = rcp_f(1.f + __expf(d));
  float xi1 = 1.f - xi0;
  *o0 = v0 * xi0;
  *o1 = v1 * xi1;
  float qd = v1 - v0;
  float q0 = rcp_f(1.f + __expf(qd));
  float q1 = 1.f - q0;
  const float LOG2F = 0.6931471805599453f;
  return q0 * (__logf(q0 + EPS_F) + LOG2F) + q1 * (__logf(q1 + EPS_F) + LOG2F);
}

__global__ __launch_bounds__(256) void k_epi(float* __restrict__ C,
                                             float* __restrict__ partial,
                                             u32 gk0, u32 gk1) {
  int idx = blockIdx.x * 256 + threadIdx.x;   // [0, 2^22)
  int b = idx >> 9;                           // 0..8191
  int c2 = (idx & 511) << 1;                  // 0,2,...,1022
  size_t p0 = (size_t)b * KU_N + c2;
  size_t p1 = p0 + (size_t)8192 * KU_N;
  float2 r0 = *(const float2*)&C[p0];
  float2 r1 = *(const float2*)&C[p1];
  u32 m = ((u32)b << 10) | (u32)c2;
  u32 x0a, x1a, x0b, x1b;
  threefry2x32(gk0, gk1, m,      m + HG,      &x0a, &x1a);
  threefry2x32(gk0, gk1, m + 1u, m + 1u + HG, &x0b, &x1b);
  float2 w0, w1;
  float kl = lwta_pair(r0.x, r0.y, x0a, x0b, &w0.x, &w0.y)
           + lwta_pair(r1.x, r1.y, x1a, x1b, &w1.x, &w1.y);
  *(float2*)&C[p0] = w0;
  *(float2*)&C[p1] = w1;
  float t = block_sum(kl);
  if (threadIdx.x == 0) partial[blockIdx.x] = t;
}

// final: kl_sticks (512 digammas) + all partial sums + combine
#define NPART 16384
__global__ __launch_bounds__(512) void k_final(const float* __restrict__ conc1,
                                               const float* __restrict__ conc0,
                                               const float* __restrict__ partial,
                                               const float* __restrict__ partialW,
                                               const float* __restrict__ partialZ,
                                               float* __restrict__ out_loss) {
  int tid = threadIdx.x;
  // kl_sticks term for this k
  float a = softplus_f(conc1[tid]);
  float b = softplus_f(conc0[tid]);
  float stick = ((a - 1.f) / a) * (-EULERC - digamma_f(b) - 1.f / b)
              + logf(a * b + EPS_F) - (b - 1.f) / b;
  float s_xi = 0.f;
  for (int i = tid; i < NPART; i += 512) s_xi += partial[i];
  float s_w = (tid < 256) ? partialW[tid] : 0.f;
  float s_z = (tid < 128) ? partialZ[tid] : 0.f;
  float v = stick + s_z + s_xi * (1.f / 32768.f)
          + s_w * (-0.5f / 1048576.f / 60000.f);
  float t = block_sum(v);
  if (tid == 0) out_loss[0] = t;
}

// ---------------- launch ----------------
extern "C" void kernel_launch(void* const* d_in, const int* in_sizes, int n_in,
                              void* d_out, int out_size, void* d_ws, size_t ws_size,
                              hipStream_t stream) {
  (void)in_sizes; (void)n_in; (void)out_size; (void)ws_size;
  const float* inputs = (const float*)d_in[0];
  const float* mW     = (const float*)d_in[1];
  const float* sW     = (const float*)d_in[2];
  const float* conc1  = (const float*)d_in[3];
  const float* conc0  = (const float*)d_in[4];
  const float* t_pi   = (const float*)d_in[5];
  const float* biases = (const float*)d_in[6];
  float* out = (float*)d_out;

  // rk[0..3] = split(key(42), 4)
  u32 a[4], b[4];
  for (int i = 0; i < 4; ++i)
    threefry2x32(0u, 42u, (u32)i, (u32)(i + 4), &a[i], &b[i]);
  u32 e_k0 = a[0], e_k1 = a[1];   // eps (normal)
  u32 u_k0 = a[2], u_k1 = a[3];   // bernoulli-u
  u32 q_k0 = b[0], q_k1 = b[1];   // kumaraswamy
  u32 g_k0 = b[2], g_k1 = b[3];   // gumbel

  char* wsb = (char*)d_ws;
  unsigned short* WzT = (unsigned short*)wsb;                     // 2MB
  float* P        = (float*)(wsb + (2u << 20));                   // 128KB
  float* partial  = (float*)(wsb + (2u << 20) + (128u << 10));    // 64KB
  float* partialW = (float*)(wsb + (2u << 20) + (192u << 10));    // 1KB
  float* partialZ = (float*)(wsb + (2u << 20) + (193u << 10));    // 512B

  hipLaunchKernelGGL(k_klz_a, dim3(128), dim3(256), 0, stream,
                     conc1, conc0, P, q_k0, q_k1);
  hipLaunchKernelGGL(k_klz_b, dim3(128), dim3(256), 0, stream,
                     t_pi, conc1, conc0, P, partialZ, q_k0, q_k1);
  hipLaunchKernelGGL(k_wbuildT, dim3(256), dim3(256), 0, stream,
                     mW, sW, t_pi, WzT, partialW, e_k0, e_k1, u_k0, u_k1);
  hipLaunchKernelGGL(k_gemm, dim3(256), dim3(512), 0, stream,
                     inputs, WzT, biases, out);
  hipLaunchKernelGGL(k_epi, dim3(NPART), dim3(256), 0, stream,
                     out, partial, g_k0, g_k1);
  hipLaunchKernelGGL(k_final, dim3(1), dim3(512), 0, stream,
                     conc1, conc0, partial, partialW, partialZ, out + 16777216);
}